// Round 2
// baseline (135.901 us; speedup 1.0000x reference)
//
#include <hip/hip_runtime.h>

// SparseConv1x1: out[b,r,hw] = sum_{k in row r} values[k] * in[b,col[k],hw]
// in/out: [8, 256, 3136] f32. nnz ~6553, CSR-sorted by row.
//
// Strategy: block = (batch b, 64-pixel tile, 128-row half).
//  - Stage all 256 channels x 16 float4-quads of the tile into LDS (64 KB).
//  - Each thread owns one quad (t&15) and 8 rows ((t>>4)*8..+8), reading
//    its row's nonzeros from the LDS tile with ds_read_b128.
//  - Reuse: each staged input element serves ~12.8 nonzeros (128 rows x 10%
//    density) from LDS instead of hammering L2 across XCDs.

#define HWQ   784    // 3136/4 float4-quads per (b,c) plane
#define CH    256
#define NF    256
#define TQ    16     // quads per tile  (64 floats)
#define NTILE 49     // HWQ / TQ
#define RB    128    // rows per block
#define RPT   8      // rows per thread = RB/16

__global__ __launch_bounds__(256, 2) void SparseConv1x1_kernel(
    const float4* __restrict__ in4,
    const float*  __restrict__ values,
    const int*    __restrict__ row_ids,
    const int*    __restrict__ col_ids,
    float4*       __restrict__ out4,
    int nnz)
{
    __shared__ float4 tile[CH * TQ];      // 64 KB, layout [c][quad]
    __shared__ int rowstart[NF + 1];

    const int t     = threadIdx.x;
    const int half  = blockIdx.x;         // 0/1: which 128 rows
    const int tl    = blockIdx.y;         // tile within image
    const int b     = blockIdx.z;
    const int qbase = tl * TQ;

    // Row offsets: each thread lower_bounds its own row r=t (L2-cached row_ids).
    {
        int lo = 0, hi = nnz;
        while (lo < hi) { int m = (lo + hi) >> 1; if (row_ids[m] < t) lo = m + 1; else hi = m; }
        rowstart[t] = lo;
        if (t == 0) rowstart[NF] = nnz;
    }

    // Stage the tile: thread t covers quad j = t&15 of channels (t>>4) + 16*i.
    // 16-lane groups read 256 B contiguous -> coalesced; LDS writes 2-way (free).
    {
        const int j  = t & 15;
        const int cb = t >> 4;
        #pragma unroll
        for (int i = 0; i < 16; ++i) {
            const int c = i * 16 + cb;
            tile[c * TQ + j] = in4[((size_t)(b * CH + c)) * HWQ + qbase + j];
        }
    }
    __syncthreads();

    const int q       = t & 15;           // quad within tile
    const int rg      = t >> 4;           // row-group 0..15
    const int rowbase = half * RB + rg * RPT;

    for (int i = 0; i < RPT; ++i) {
        const int r   = rowbase + i;
        int       k   = rowstart[r];
        const int end = rowstart[r + 1];

        float4 acc0 = make_float4(0.f, 0.f, 0.f, 0.f);
        float4 acc1 = make_float4(0.f, 0.f, 0.f, 0.f);

        for (; k + 1 < end; k += 2) {
            const float v0 = values[k];
            const int   c0 = col_ids[k];
            const float v1 = values[k + 1];
            const int   c1 = col_ids[k + 1];
            const float4 x0 = tile[c0 * TQ + q];
            const float4 x1 = tile[c1 * TQ + q];
            acc0.x = fmaf(v0, x0.x, acc0.x);
            acc0.y = fmaf(v0, x0.y, acc0.y);
            acc0.z = fmaf(v0, x0.z, acc0.z);
            acc0.w = fmaf(v0, x0.w, acc0.w);
            acc1.x = fmaf(v1, x1.x, acc1.x);
            acc1.y = fmaf(v1, x1.y, acc1.y);
            acc1.z = fmaf(v1, x1.z, acc1.z);
            acc1.w = fmaf(v1, x1.w, acc1.w);
        }
        if (k < end) {
            const float v0 = values[k];
            const int   c0 = col_ids[k];
            const float4 x0 = tile[c0 * TQ + q];
            acc0.x = fmaf(v0, x0.x, acc0.x);
            acc0.y = fmaf(v0, x0.y, acc0.y);
            acc0.z = fmaf(v0, x0.z, acc0.z);
            acc0.w = fmaf(v0, x0.w, acc0.w);
        }

        float4 acc;
        acc.x = acc0.x + acc1.x;
        acc.y = acc0.y + acc1.y;
        acc.z = acc0.z + acc1.z;
        acc.w = acc0.w + acc1.w;
        out4[((size_t)(b * NF + r)) * HWQ + qbase + q] = acc;
    }
}

extern "C" void kernel_launch(void* const* d_in, const int* in_sizes, int n_in,
                              void* d_out, int out_size, void* d_ws, size_t ws_size,
                              hipStream_t stream) {
    const float* inputs  = (const float*)d_in[0];
    const float* values  = (const float*)d_in[1];
    const int*   row_ids = (const int*)  d_in[2];
    const int*   col_ids = (const int*)  d_in[3];
    const int nnz = in_sizes[1];

    // x = row-half (2) fastest so both halves of a tile dispatch adjacently
    // (share the staged data in L2); y = tile (49); z = batch (8).
    dim3 grid(2, NTILE, 8);
    SparseConv1x1_kernel<<<grid, dim3(256, 1, 1), 0, stream>>>(
        (const float4*)inputs, values, row_ids, col_ids, (float4*)d_out, nnz);
}

// Round 3
// 116.051 us; speedup vs baseline: 1.1710x; 1.1710x over previous
//
#include <hip/hip_runtime.h>

// SparseConv1x1: out[b,r,hw] = sum_{k in row r} values[k] * in[b,col[k],hw]
// in/out: [8, 256, 3136] f32. nnz ~6553, CSR-sorted by row.
//
// R3: latency-hiding rework of the LDS-tiled kernel.
//  - TQ=8 (32-pixel tile, 32 KB LDS) -> 4 blocks/CU, 16 waves/CU (50% occ).
//  - k-loop unrolled x4 with 4 independent accumulator chains.
//  - Prep kernel packs (col*TQ, value) into int2 in d_ws: one 8B load per nz
//    in the hot loop instead of two 4B loads from separate arrays.

#define HWQ    784   // 3136/4 float4-quads per (b,c) plane
#define CH     256
#define NF     256
#define TQ     8     // float4-quads per tile (32 pixels)
#define NTILE  98    // HWQ / TQ
#define RB     128   // rows per block
#define RGRP   32    // row-groups = 256 threads / TQ
#define RPT    4     // rows per thread = RB / RGRP

__global__ __launch_bounds__(256) void pack_kernel(
    const float* __restrict__ values,
    const int*   __restrict__ col_ids,
    int2*        __restrict__ pk,
    int nnz)
{
    int i = blockIdx.x * 256 + threadIdx.x;
    if (i < nnz) pk[i] = make_int2(col_ids[i] * TQ, __float_as_int(values[i]));
}

__global__ __launch_bounds__(256, 4) void SparseConv1x1_kernel(
    const float4* __restrict__ in4,
    const int2*   __restrict__ pk,       // packed (col*TQ, value_bits)
    const int*    __restrict__ row_ids,
    float4*       __restrict__ out4,
    int nnz)
{
    __shared__ float4 tile[CH * TQ];     // 32 KB, layout [c][quad]
    __shared__ int rowstart[NF + 1];

    const int t     = threadIdx.x;
    const int half  = blockIdx.x;        // 0/1: which 128 rows
    const int tl    = blockIdx.y;        // tile within image
    const int b     = blockIdx.z;
    const int qbase = tl * TQ;

    // Row offsets: thread t lower_bounds row t (row_ids is tiny, L2-hot).
    {
        int lo = 0, hi = nnz;
        while (lo < hi) { int m = (lo + hi) >> 1; if (row_ids[m] < t) lo = m + 1; else hi = m; }
        rowstart[t] = lo;
        if (t == 0) rowstart[NF] = nnz;
    }

    // Stage tile: 2048 float4s, 8 per thread. Flat index i = c*TQ + j, so
    // consecutive lanes write consecutive LDS and read coalesced 128B runs.
    #pragma unroll
    for (int i = 0; i < 8; ++i) {
        const int idx = i * 256 + t;
        const int c   = idx >> 3;        // idx / TQ
        const int j   = idx & 7;         // idx % TQ
        tile[idx] = in4[((size_t)(b * CH + c)) * HWQ + qbase + j];
    }
    __syncthreads();

    const int q       = t & 7;           // quad within tile
    const int rg      = t >> 3;          // row-group 0..31
    const int rowbase = half * RB + rg * RPT;

    #pragma unroll
    for (int i = 0; i < RPT; ++i) {
        const int r   = rowbase + i;
        int       k   = rowstart[r];
        const int end = rowstart[r + 1];

        float4 a0 = make_float4(0.f, 0.f, 0.f, 0.f);
        float4 a1 = make_float4(0.f, 0.f, 0.f, 0.f);
        float4 a2 = make_float4(0.f, 0.f, 0.f, 0.f);
        float4 a3 = make_float4(0.f, 0.f, 0.f, 0.f);

        for (; k + 4 <= end; k += 4) {
            const int2 p0 = pk[k];
            const int2 p1 = pk[k + 1];
            const int2 p2 = pk[k + 2];
            const int2 p3 = pk[k + 3];
            const float4 x0 = tile[p0.x + q];
            const float4 x1 = tile[p1.x + q];
            const float4 x2 = tile[p2.x + q];
            const float4 x3 = tile[p3.x + q];
            const float v0 = __int_as_float(p0.y);
            const float v1 = __int_as_float(p1.y);
            const float v2 = __int_as_float(p2.y);
            const float v3 = __int_as_float(p3.y);
            a0.x = fmaf(v0, x0.x, a0.x); a0.y = fmaf(v0, x0.y, a0.y);
            a0.z = fmaf(v0, x0.z, a0.z); a0.w = fmaf(v0, x0.w, a0.w);
            a1.x = fmaf(v1, x1.x, a1.x); a1.y = fmaf(v1, x1.y, a1.y);
            a1.z = fmaf(v1, x1.z, a1.z); a1.w = fmaf(v1, x1.w, a1.w);
            a2.x = fmaf(v2, x2.x, a2.x); a2.y = fmaf(v2, x2.y, a2.y);
            a2.z = fmaf(v2, x2.z, a2.z); a2.w = fmaf(v2, x2.w, a2.w);
            a3.x = fmaf(v3, x3.x, a3.x); a3.y = fmaf(v3, x3.y, a3.y);
            a3.z = fmaf(v3, x3.z, a3.z); a3.w = fmaf(v3, x3.w, a3.w);
        }
        for (; k < end; ++k) {
            const int2 p0 = pk[k];
            const float4 x0 = tile[p0.x + q];
            const float v0 = __int_as_float(p0.y);
            a0.x = fmaf(v0, x0.x, a0.x); a0.y = fmaf(v0, x0.y, a0.y);
            a0.z = fmaf(v0, x0.z, a0.z); a0.w = fmaf(v0, x0.w, a0.w);
        }

        float4 acc;
        acc.x = (a0.x + a1.x) + (a2.x + a3.x);
        acc.y = (a0.y + a1.y) + (a2.y + a3.y);
        acc.z = (a0.z + a1.z) + (a2.z + a3.z);
        acc.w = (a0.w + a1.w) + (a2.w + a3.w);
        out4[((size_t)(b * NF + r)) * HWQ + qbase + q] = acc;
    }
}

extern "C" void kernel_launch(void* const* d_in, const int* in_sizes, int n_in,
                              void* d_out, int out_size, void* d_ws, size_t ws_size,
                              hipStream_t stream) {
    const float* inputs  = (const float*)d_in[0];
    const float* values  = (const float*)d_in[1];
    const int*   row_ids = (const int*)  d_in[2];
    const int*   col_ids = (const int*)  d_in[3];
    const int nnz = in_sizes[1];

    int2* pk = (int2*)d_ws;
    pack_kernel<<<(nnz + 255) / 256, dim3(256, 1, 1), 0, stream>>>(
        values, col_ids, pk, nnz);

    dim3 grid(2, NTILE, 8);
    SparseConv1x1_kernel<<<grid, dim3(256, 1, 1), 0, stream>>>(
        (const float4*)inputs, pk, row_ids, (float4*)d_out, nnz);
}